// Round 2
// baseline (841.343 us; speedup 1.0000x reference)
//
#include <hip/hip_runtime.h>
#include <math.h>

#define SEQ   1024
#define BATCH 1024
#define IN_F  57
#define H_F   128
#define OUT_F 18
#define MROWS 16     // batch rows per block
#define HSTR  136    // h_lds row stride in bf16 (272 B, 16B-aligned)
#define XSTR  72     // x_lds row stride in bf16 (144 B)

typedef __attribute__((ext_vector_type(8))) short bf8;     // MFMA A/B frag
typedef __attribute__((ext_vector_type(4))) float f32x4;   // MFMA C/D frag

static __device__ __forceinline__ short f2bf(float f) {    // fp32 -> bf16 RNE
    unsigned u = __builtin_bit_cast(unsigned, f);
    u = (u + 0x7FFFu + ((u >> 16) & 1u)) >> 16;
    return (short)u;
}
static __device__ __forceinline__ float bf2f(short s) {
    unsigned u = ((unsigned)(unsigned short)s) << 16;
    return __builtin_bit_cast(float, u);
}

// 64 blocks x 256 threads, block owns 16 batch rows for the whole sequence.
// Wave wv owns output cols [32wv, 32wv+32) as two 16x16x32 bf16 MFMA tiles.
// Per-step critical path is the whole ballgame (1 block/CU, all blocks run the
// same 1024 serial steps concurrently).
// R5/R6: __syncthreads() compiles to "s_waitcnt vmcnt(0) lgkmcnt(0); s_barrier",
// which drains the x_{t+3} prefetch EVERY STEP and exposes a full cold-HBM
// latency (~375 ns) on the serial chain — this is why the depth-2 prefetch was
// a no-op. Replace the per-step barrier with "s_waitcnt lgkmcnt(0)" +
// __builtin_amdgcn_s_barrier() so global loads stay in flight across steps;
// the compiler's own counted vmcnt at the XS use (2 steps later) guards
// consumption. (R6 = R5 rerun after container-level infra failure; barrier
// idiom switched to the builtin form verified in the 8-phase GEMM template.)
__global__ __launch_bounds__(256) void rnn_mfma_kernel(
    const float* __restrict__ X,     // [SEQ][BATCH][IN_F]
    const float* __restrict__ W_ih,  // [H_F][IN_F]
    const float* __restrict__ b_ih,  // [H_F]
    const float* __restrict__ W_hh,  // [H_F][H_F]
    const float* __restrict__ b_hh,  // [H_F]
    const float* __restrict__ W_ho,  // [OUT_F][H_F]
    const float* __restrict__ b_ho,  // [OUT_F]
    float* __restrict__ out)         // [BATCH][OUT_F] ++ [BATCH][H_F]
{
    const int tid  = threadIdx.x;
    const int lane = tid & 63;
    const int wv   = tid >> 6;
    const int n16  = lane & 15;
    const int quad = lane >> 4;
    const int b0   = blockIdx.x * MROWS;

    __shared__ short h_lds[2][MROWS][HSTR];
    __shared__ short x_lds[2][MROWS][XSTR];
    __shared__ float logits_lds[MROWS][OUT_F];
    __shared__ float red_lds[MROWS][2];

    const int j0 = wv * 32 + n16;
    const int j1 = j0 + 16;

    // ---- W_hh B-frags (bf16) in registers ----
    const float* wp0 = W_hh + j0 * H_F + quad * 8;
    const float* wp1 = W_hh + j1 * H_F + quad * 8;
#define LDW8(P) ({ \
        f32x4 p_ = *(const f32x4*)(P); \
        f32x4 q_ = *(const f32x4*)((P) + 4); \
        bf8 f_; \
        f_[0]=f2bf(p_[0]); f_[1]=f2bf(p_[1]); f_[2]=f2bf(p_[2]); f_[3]=f2bf(p_[3]); \
        f_[4]=f2bf(q_[0]); f_[5]=f2bf(q_[1]); f_[6]=f2bf(q_[2]); f_[7]=f2bf(q_[3]); \
        f_; })
    bf8 wh00 = LDW8(wp0 +  0), wh01 = LDW8(wp0 + 32), wh02 = LDW8(wp0 + 64), wh03 = LDW8(wp0 + 96);
    bf8 wh10 = LDW8(wp1 +  0), wh11 = LDW8(wp1 + 32), wh12 = LDW8(wp1 + 64), wh13 = LDW8(wp1 + 96);

    // ---- W_ih B-frags (K 57->64 zero-pad) ----
#define LDWI(J, KS) ({ \
        bf8 f_; \
        _Pragma("unroll") \
        for (int i_ = 0; i_ < 8; ++i_) { \
            int k_ = (KS) * 32 + quad * 8 + i_; \
            f_[i_] = (k_ < IN_F) ? f2bf(W_ih[(J) * IN_F + k_]) : (short)0; \
        } f_; })
    bf8 wi00 = LDWI(j0, 0), wi01 = LDWI(j0, 1), wi10 = LDWI(j1, 0), wi11 = LDWI(j1, 1);

    const float bias0 = b_ih[j0] + b_hh[j0];
    const float bias1 = b_ih[j1] + b_hh[j1];

    // ---- x staging constants: 912 floats/step = 228 f32x4 lanes ----
    const bool  xlane = (tid < 228);
    const size_t tstride = (size_t)BATCH * IN_F;
    const float* xbase = X + (size_t)b0 * IN_F + tid * 4;
    // per-element LDS targets for this lane's 4 floats
    int xm[4], xk[4];
    #pragma unroll
    for (int e = 0; e < 4; ++e) {
        int idx = tid * 4 + e;
        xm[e] = (int)((unsigned)idx / 57u);
        xk[e] = idx - xm[e] * 57;
    }

    // ---- init: h0 = 0, zero x pads, stage x_0 directly, prefetch x_1, x_2 ----
    for (int i = tid; i < MROWS * HSTR; i += 256) (&h_lds[0][0][0])[i] = 0;
    for (int i = tid; i < 2 * MROWS * XSTR; i += 256) (&x_lds[0][0][0])[i] = 0;
    f32x4 xq0 = {0,0,0,0}, xq1 = {0,0,0,0};
    if (xlane) {
        f32x4 v = *(const f32x4*)(xbase);
        #pragma unroll
        for (int e = 0; e < 4; ++e) x_lds[0][xm[e]][xk[e]] = f2bf(v[e]);
        xq1 = *(const f32x4*)(xbase + 1 * tstride);   // x_1  (written at T=0)
        xq0 = *(const f32x4*)(xbase + 2 * tstride);   // x_2  (written at T=1)
    }
    __syncthreads();

    // Raw barrier: cross-wave LDS visibility needs only lgkmcnt(0) before
    // s_barrier. Crucially does NOT drain vmcnt, so the x prefetch loads
    // stay in flight across steps ("never vmcnt(0) in the main loop").
    // "memory" clobber pins LDS reads/writes on the correct side.
#define STEP_BARRIER() do { \
        asm volatile("s_waitcnt lgkmcnt(0)" ::: "memory"); \
        __builtin_amdgcn_s_barrier(); \
    } while (0)

#define MFMA __builtin_amdgcn_mfma_f32_16x16x32_bf16
#define STEP(CB, NB, T, XS) do { \
        /* A-frags for this step */ \
        const short* hc = &h_lds[CB][0][0] + n16 * HSTR + quad * 8; \
        const short* xc = &x_lds[CB][0][0] + n16 * XSTR + quad * 8; \
        bf8 ah0 = *(const bf8*)(hc +  0); \
        bf8 ah1 = *(const bf8*)(hc + 32); \
        bf8 ah2 = *(const bf8*)(hc + 64); \
        bf8 ah3 = *(const bf8*)(hc + 96); \
        bf8 ax0 = *(const bf8*)(xc +  0); \
        bf8 ax1 = *(const bf8*)(xc + 32); \
        /* stage x_{T+1} (loaded 2 steps ago -> no vmcnt stall) into NB now */ \
        if (((T) + 1 < SEQ) && xlane) { \
            _Pragma("unroll") \
            for (int e = 0; e < 4; ++e) x_lds[NB][xm[e]][xk[e]] = f2bf(XS[e]); \
        } \
        /* issue load of x_{T+3} into the same parity slot */ \
        if (((T) + 3 < SEQ) && xlane) \
            XS = *(const f32x4*)(xbase + (size_t)((T) + 3) * tstride); \
        /* 12 MFMAs, 4 chains of depth 3 */ \
        f32x4 c0a = {bias0, bias0, bias0, bias0}, c0b = {0.f, 0.f, 0.f, 0.f}; \
        f32x4 c1a = {bias1, bias1, bias1, bias1}, c1b = {0.f, 0.f, 0.f, 0.f}; \
        c0a = MFMA(ah0, wh00, c0a, 0, 0, 0); \
        c1a = MFMA(ah0, wh10, c1a, 0, 0, 0); \
        c0b = MFMA(ah1, wh01, c0b, 0, 0, 0); \
        c1b = MFMA(ah1, wh11, c1b, 0, 0, 0); \
        c0a = MFMA(ah2, wh02, c0a, 0, 0, 0); \
        c1a = MFMA(ah2, wh12, c1a, 0, 0, 0); \
        c0b = MFMA(ah3, wh03, c0b, 0, 0, 0); \
        c1b = MFMA(ah3, wh13, c1b, 0, 0, 0); \
        c0a = MFMA(ax0, wi00, c0a, 0, 0, 0); \
        c1a = MFMA(ax0, wi10, c1a, 0, 0, 0); \
        c0b = MFMA(ax1, wi01, c0b, 0, 0, 0); \
        c1b = MFMA(ax1, wi11, c1b, 0, 0, 0); \
        short* hn = &h_lds[NB][0][0]; \
        _Pragma("unroll") \
        for (int r = 0; r < 4; ++r) { \
            int m = quad * 4 + r; \
            float z0 = fminf(fmaxf(c0a[r] + c0b[r], -9.f), 9.f); \
            float e0 = __expf(2.f * z0); \
            hn[m * HSTR + j0] = f2bf((e0 - 1.f) * __builtin_amdgcn_rcpf(e0 + 1.f)); \
            float z1 = fminf(fmaxf(c1a[r] + c1b[r], -9.f), 9.f); \
            float e1 = __expf(2.f * z1); \
            hn[m * HSTR + j1] = f2bf((e1 - 1.f) * __builtin_amdgcn_rcpf(e1 + 1.f)); \
        } \
        STEP_BARRIER(); \
    } while (0)

    for (int t = 0; t < SEQ; t += 2) {
        STEP(0, 1, t,     xq1);
        STEP(1, 0, t + 1, xq0);
    }
#undef STEP
#undef MFMA

    // ---- final h (buf0) -> hT ----
    float* hT = out + (size_t)BATCH * OUT_F;
    #pragma unroll
    for (int r = 0; r < (MROWS * H_F) / 256; ++r) {
        int idx = tid + r * 256;
        int m = idx >> 7, k = idx & 127;
        hT[(size_t)(b0 + m) * H_F + k] = bf2f(h_lds[0][m][k]);
    }

    // ---- logits [16][18] ----
    for (int idx = tid; idx < MROWS * OUT_F; idx += 256) {
        int m = idx / OUT_F, o = idx - m * OUT_F;
        float acc = b_ho[o];
        for (int k = 0; k < H_F; ++k)
            acc = fmaf(bf2f(h_lds[0][m][k]), W_ho[o * H_F + k], acc);
        logits_lds[m][o] = acc;
    }
    __syncthreads();

    if (tid < MROWS) {
        float mx = -1e30f;
        #pragma unroll
        for (int o = 0; o < OUT_F; ++o) mx = fmaxf(mx, logits_lds[tid][o]);
        float s = 0.f;
        #pragma unroll
        for (int o = 0; o < OUT_F; ++o) s += expf(logits_lds[tid][o] - mx);
        red_lds[tid][0] = mx;
        red_lds[tid][1] = logf(s);
    }
    __syncthreads();

    for (int idx = tid; idx < MROWS * OUT_F; idx += 256) {
        int m = idx / OUT_F, o = idx - m * OUT_F;
        out[(size_t)(b0 + m) * OUT_F + o] =
            logits_lds[m][o] - red_lds[m][0] - red_lds[m][1];
    }
}

extern "C" void kernel_launch(void* const* d_in, const int* in_sizes, int n_in,
                              void* d_out, int out_size, void* d_ws, size_t ws_size,
                              hipStream_t stream) {
    const float* X    = (const float*)d_in[0];
    const float* W_ih = (const float*)d_in[1];
    const float* b_ih = (const float*)d_in[2];
    const float* W_hh = (const float*)d_in[3];
    const float* b_hh = (const float*)d_in[4];
    const float* W_ho = (const float*)d_in[5];
    const float* b_ho = (const float*)d_in[6];
    float* out = (float*)d_out;

    rnn_mfma_kernel<<<dim3(BATCH / MROWS), dim3(256), 0, stream>>>(
        X, W_ih, b_ih, W_hh, b_hh, W_ho, b_ho, out);
}